// Round 5
// baseline (169.532 us; speedup 1.0000x reference)
//
#include <hip/hip_runtime.h>
#include <hip/hip_bf16.h>

typedef __attribute__((ext_vector_type(8))) short short8;
typedef __attribute__((ext_vector_type(4))) float f32x4;
typedef __attribute__((ext_vector_type(2))) unsigned int u32x2;
typedef __attribute__((ext_vector_type(4))) unsigned int u32x4;

#define SLAB 9216      // bytes per slot slab: 144 rows x 64B (32 bf16)
#define BUFB 18432     // per-step buffer: 2 slots

// involution swizzle: XOR bank-group bits (4-5) with row bits (7-8)
__device__ __forceinline__ unsigned sw(unsigned off) {
  return off ^ (((off >> 7) & 3u) << 4);
}

__device__ __forceinline__ unsigned pk2(float lo, float hi) {
  union { __hip_bfloat162 h; unsigned u; } c;
  c.h = __float22bfloat162_rn(float2{lo, hi});
  return c.u;
}

// one-time: ker (fp32, N*K x F x C) -> bf16 fragment-linear in ws
// frag(ch,nk,ft,lane) holds W[f=ft*16+(lane&15), c=ch*32+(lane>>4)*8 .. +8]
extern "C" __global__ void w_prep(const float* __restrict__ ker, u32x4* __restrict__ wsw) {
  const int nk = blockIdx.x % 36;
  const int ch = blockIdx.x / 36;
  const int lane = threadIdx.x & 63;
  const int ft = threadIdx.x >> 6;
  const float* src = ker + (size_t)(nk * 64 + ft * 16 + (lane & 15)) * 64
                         + ch * 32 + (lane >> 4) * 8;
  f32x4 a0 = *(const f32x4*)src;
  f32x4 a1 = *(const f32x4*)(src + 4);
  u32x4 h = { pk2(a0.x, a0.y), pk2(a0.z, a0.w), pk2(a1.x, a1.y), pk2(a1.z, a1.w) };
  wsw[((ch * 36 + nk) * 4 + ft) * 64 + lane] = h;
}

extern "C" __global__ __launch_bounds__(256, 2)
void glc_mfma(const float* __restrict__ x, const short8* __restrict__ wsw,
              const int* __restrict__ nb, float* __restrict__ out) {
  __shared__ __align__(16) char xs[2 * BUFB];

  const int bid = blockIdx.x;
  const int tt = bid % 5;
  const int up = (bid / 5) % 13;
  const int a  = (bid / 65) % 3;
  const int b  = bid / 195;
  const int t0 = tt * 64;
  const int u0 = up * 2;
  const bool updup = (up == 12);   // u-pair (24,24): waves 2,3 duplicate

  const int tid  = threadIdx.x;
  const int lane = tid & 63;
  const int wave = tid >> 6;
  const int uloc = wave >> 1;

  const int su0 = u0;
  const int su1 = updup ? u0 : (u0 + 1);

  // B-fragment swizzled offsets: addr = buf + uloc*SLAB + (k>>2)*512 + poff[i][k&3]
  const int rl = lane & 15, gq = lane >> 4;
  unsigned poff[4][4];
#pragma unroll
  for (int i = 0; i < 4; ++i) {
    const int ctl = (wave * 4 + i) & 7;
#pragma unroll
    for (int m = 0; m < 4; ++m)
      poff[i][m] = sw((unsigned)((ctl * 16 + 2 * m + rl) * 64 + gq * 16));
  }

  f32x4 acc[4][4];
#pragma unroll
  for (int i = 0; i < 4; ++i)
#pragma unroll
    for (int j = 0; j < 4; ++j) acc[i][j] = (f32x4){0.f, 0.f, 0.f, 0.f};

  const float* xb = x + (size_t)b * (300 * 9600) + (size_t)a * 3200;

  // ---------------- staging helpers (inlined via lambdas) ----------------
  f32x4 sr[9];
  auto stage_load = [&](int snx) {
    const int n2 = snx >> 1, ch2 = snx & 1;
    const int v0 = nb[su0 * 4 + n2];
    const int v1 = nb[su1 * 4 + n2];
#pragma unroll
    for (int j = 0; j < 9; ++j) {
      const int u = j * 256 + tid;
      const int slot = (u >= 1152) ? 1 : 0;
      const int rem = u - slot * 1152;
      const int r = rem >> 3, q = rem & 7;
      int t = t0 + (r >> 1); if (t > 299) t = 299;   // clamp; garbage discarded
      const int vp = (slot ? v1 : v0) * 2 + (r & 1);
      sr[j] = *(const f32x4*)(xb + (size_t)t * 9600 + vp * 64 + ch2 * 32 + q * 4);
    }
  };
  auto stage_write = [&](int snx) {
    char* dst = xs + (snx & 1) * BUFB;
#pragma unroll
    for (int j = 0; j < 9; ++j) {
      const int u = j * 256 + tid;
      const int slot = (u >= 1152) ? 1 : 0;
      const int rem = u - slot * 1152;
      const int r = rem >> 3, q = rem & 7;
      u32x2 h = { pk2(sr[j].x, sr[j].y), pk2(sr[j].z, sr[j].w) };
      *(u32x2*)(dst + slot * SLAB + sw((unsigned)(r * 64 + q * 8))) = h;
    }
  };

  // ---------------- prologue: stage step 0, load W(0,0) ----------------
  stage_load(0);
  stage_write(0);
  short8 wcur[4];
#pragma unroll
  for (int ft = 0; ft < 4; ++ft) wcur[ft] = wsw[ft * 64 + lane];
  __syncthreads();

  // ---------------- main loop: 8 steps of (n = s>>1, ch = s&1) ----------------
#pragma unroll 1
  for (int s = 0; s < 8; ++s) {
    const int wbase = (s & 1) * 9216 + (s >> 1) * 2304;          // short8 units
    const int wbase_next = ((s + 1) & 1) * 9216 + ((s + 1) >> 1) * 2304;
    if (s < 7) stage_load(s + 1);        // issue next-step x loads (overlap compute)

    const unsigned cb = (unsigned)((s & 1) * BUFB + uloc * SLAB);
#pragma unroll
    for (int k = 0; k < 9; ++k) {
      // rolling 1-deep W prefetch (global, L2-resident)
      short8 wnxt[4];
      const int woff = (k < 8) ? (wbase + (k + 1) * 256) : wbase_next;
#pragma unroll
      for (int ft = 0; ft < 4; ++ft) wnxt[ft] = wsw[woff + ft * 64 + lane];
      const unsigned kq = cb + (unsigned)((k >> 2) * 512);
#pragma unroll
      for (int i = 0; i < 4; ++i) {
        short8 bv = *(const short8*)(xs + (kq + poff[i][k & 3]));
#pragma unroll
        for (int ft = 0; ft < 4; ++ft)
          acc[ft][i] = __builtin_amdgcn_mfma_f32_16x16x32_bf16(wcur[ft], bv, acc[ft][i], 0, 0, 0);
      }
#pragma unroll
      for (int ft = 0; ft < 4; ++ft) wcur[ft] = wnxt[ft];
    }

    if (s < 7) {
      stage_write(s + 1);                // vmcnt wait lands here, after compute
      __syncthreads();
    }
  }

  // ---- epilogue: D tile (ft,i): col = lane&15, f = ft*16 + (lane>>4)*4 + reg ----
  if (updup && uloc) return;            // skip duplicate u=24 stores
  const int u = u0 + uloc;
  const int fbase = (lane >> 4) * 4;
  const f32x4 z4 = (f32x4){0.f, 0.f, 0.f, 0.f};
#pragma unroll
  for (int i = 0; i < 4; ++i) {
    const int colg = wave * 64 + i * 16 + (lane & 15);
    const int cc = colg & 127;          // within-u column: t-rel (p-minor)
    const int t = t0 + (cc >> 1);
    const int p = cc & 1;
    if (t < 300) {
      float* dst = out + ((size_t)((b * 300 + t) * 3 + a) * 50 + (u * 2 + p)) * 64 + fbase;
      const bool valid = (t < 292);     // t>=292: zero-pad tail
#pragma unroll
      for (int ft = 0; ft < 4; ++ft) {
        f32x4 v = valid ? acc[ft][i] : z4;
        *(f32x4*)(dst + ft * 16) = v;
      }
    }
  }
}

extern "C" void kernel_launch(void* const* d_in, const int* in_sizes, int n_in,
                              void* d_out, int out_size, void* d_ws, size_t ws_size,
                              hipStream_t stream) {
  const float* x   = (const float*)d_in[0];
  const float* ker = (const float*)d_in[1];
  const int*   nb  = (const int*)d_in[2];
  float* out = (float*)d_out;

  w_prep<<<dim3(72), dim3(256), 0, stream>>>(ker, (u32x4*)d_ws);
  glc_mfma<<<dim3(8 * 3 * 13 * 5), dim3(256), 0, stream>>>(x, (const short8*)d_ws, nb, out);
}

// Round 6
// 162.836 us; speedup vs baseline: 1.0411x; 1.0411x over previous
//
#include <hip/hip_runtime.h>
#include <hip/hip_bf16.h>

typedef __attribute__((ext_vector_type(8))) short short8;
typedef __attribute__((ext_vector_type(4))) float f32x4;
typedef __attribute__((ext_vector_type(2))) unsigned int u32x2;
typedef __attribute__((ext_vector_type(4))) unsigned int u32x4;

#define SLAB 9216      // bytes per slot slab: 144 rows x 64B (32 bf16)
#define BUFB 18432     // per-step buffer: 2 slots

// involution swizzle: XOR bank-group bits (4-5) with row bits (7-8)
__device__ __forceinline__ unsigned sw(unsigned off) {
  return off ^ (((off >> 7) & 3u) << 4);
}

__device__ __forceinline__ unsigned pk2(float lo, float hi) {
  union { __hip_bfloat162 h; unsigned u; } c;
  c.h = __float22bfloat162_rn(float2{lo, hi});
  return c.u;
}

// one-time: ker (fp32, N*K x F x C) -> bf16 fragment-linear in ws
// frag(ch,nk,ft,lane) holds W[f=ft*16+(lane&15), c=ch*32+(lane>>4)*8 .. +8]
extern "C" __global__ void w_prep(const float* __restrict__ ker, u32x4* __restrict__ wsw) {
  const int nk = blockIdx.x % 36;
  const int ch = blockIdx.x / 36;
  const int lane = threadIdx.x & 63;
  const int ft = threadIdx.x >> 6;
  const float* src = ker + (size_t)(nk * 64 + ft * 16 + (lane & 15)) * 64
                         + ch * 32 + (lane >> 4) * 8;
  f32x4 a0 = *(const f32x4*)src;
  f32x4 a1 = *(const f32x4*)(src + 4);
  u32x4 h = { pk2(a0.x, a0.y), pk2(a0.z, a0.w), pk2(a1.x, a1.y), pk2(a1.z, a1.w) };
  wsw[((ch * 36 + nk) * 4 + ft) * 64 + lane] = h;
}

extern "C" __global__ __launch_bounds__(512, 4)
void glc_mfma(const float* __restrict__ x, const short8* __restrict__ wsw,
              const int* __restrict__ nb, float* __restrict__ out) {
  __shared__ __align__(16) char xs[2 * BUFB];

  const int bid = blockIdx.x;
  const int tt = bid % 5;
  const int up = (bid / 5) % 13;
  const int a  = (bid / 65) % 3;
  const int b  = bid / 195;
  const int t0 = tt * 64;
  const int u0 = up * 2;
  const bool updup = (up == 12);   // u-pair (24,24): odd waves duplicate

  const int tid  = threadIdx.x;
  const int lane = tid & 63;
  const int wave = tid >> 6;           // 0..7
  const int uloc = wave & 1;           // which u of the pair
  const int fhalf = (wave >> 1) & 1;   // which pair of f-tiles (f 0-31 / 32-63)
  const int tq   = wave >> 2;          // which 4 col-tiles of the u-slot

  const int su0 = u0;
  const int su1 = updup ? u0 : (u0 + 1);

  // B-fragment swizzled offsets: addr = (s&1)*BUFB + uloc*SLAB + tq*4096
  //                                   + i*1024 + (k>>2)*512 + poff[k&3]
  // (adds of 512/1024/4096 never touch swizzle-key bits 7-8)
  const int rl = lane & 15, gq = lane >> 4;
  unsigned poff[4];
#pragma unroll
  for (int m = 0; m < 4; ++m)
    poff[m] = sw((unsigned)((2 * m + rl) * 64 + gq * 16));

  f32x4 acc[2][4];
#pragma unroll
  for (int j = 0; j < 2; ++j)
#pragma unroll
    for (int i = 0; i < 4; ++i) acc[j][i] = (f32x4){0.f, 0.f, 0.f, 0.f};

  const float* xb = x + (size_t)b * (300 * 9600) + (size_t)a * 3200;

  // ---------------- staging (2304 f32x4 per step over 512 threads) ----------------
  f32x4 sr[5];
  auto stage_load = [&](int snx) {
    const int n2 = snx >> 1, ch2 = snx & 1;
    const int v0 = nb[su0 * 4 + n2];
    const int v1 = nb[su1 * 4 + n2];
#pragma unroll
    for (int j = 0; j < 5; ++j) {
      const int u = j * 512 + tid;
      if (u < 2304) {
        const int slot = (u >= 1152) ? 1 : 0;
        const int rem = u - slot * 1152;
        const int r = rem >> 3, q = rem & 7;
        int t = t0 + (r >> 1); if (t > 299) t = 299;   // clamp; garbage discarded
        const int vp = (slot ? v1 : v0) * 2 + (r & 1);
        sr[j] = *(const f32x4*)(xb + (size_t)t * 9600 + vp * 64 + ch2 * 32 + q * 4);
      }
    }
  };
  auto stage_write = [&](int snx) {
    char* dst = xs + (snx & 1) * BUFB;
#pragma unroll
    for (int j = 0; j < 5; ++j) {
      const int u = j * 512 + tid;
      if (u < 2304) {
        const int slot = (u >= 1152) ? 1 : 0;
        const int rem = u - slot * 1152;
        const int r = rem >> 3, q = rem & 7;
        u32x2 h = { pk2(sr[j].x, sr[j].y), pk2(sr[j].z, sr[j].w) };
        *(u32x2*)(dst + slot * SLAB + sw((unsigned)(r * 64 + q * 8))) = h;
      }
    }
  };

  // ---------------- prologue: stage step 0, load W(0,0) ----------------
  stage_load(0);
  stage_write(0);
  short8 wcur[2];
#pragma unroll
  for (int j = 0; j < 2; ++j) wcur[j] = wsw[(fhalf * 2 + j) * 64 + lane];
  __syncthreads();

  // ---------------- main loop: 8 steps of (n = s>>1, ch = s&1) ----------------
#pragma unroll 1
  for (int s = 0; s < 8; ++s) {
    const int wbase = (s & 1) * 9216 + (s >> 1) * 2304 + fhalf * 128;   // short8 units
    const int wbase_next = (s < 7)
        ? (((s + 1) & 1) * 9216 + ((s + 1) >> 1) * 2304 + fhalf * 128) : wbase;
    if (s < 7) stage_load(s + 1);        // issue next-step x loads (overlap compute)

    const unsigned cb = (unsigned)((s & 1) * BUFB + uloc * SLAB + tq * 4096);
#pragma unroll
    for (int k = 0; k < 9; ++k) {
      // rolling 1-deep W prefetch (global, L1/L2-resident)
      short8 wnxt[2];
      const int woff = (k < 8) ? (wbase + (k + 1) * 256) : wbase_next;
#pragma unroll
      for (int j = 0; j < 2; ++j) wnxt[j] = wsw[woff + j * 64 + lane];
      const unsigned kq = cb + (unsigned)((k >> 2) * 512) + poff[k & 3];
#pragma unroll
      for (int i = 0; i < 4; ++i) {
        short8 bv = *(const short8*)(xs + (kq + (unsigned)(i * 1024)));
#pragma unroll
        for (int j = 0; j < 2; ++j)
          acc[j][i] = __builtin_amdgcn_mfma_f32_16x16x32_bf16(wcur[j], bv, acc[j][i], 0, 0, 0);
      }
#pragma unroll
      for (int j = 0; j < 2; ++j) wcur[j] = wnxt[j];
    }

    if (s < 7) {
      stage_write(s + 1);                // vmcnt wait lands here, after compute
      __syncthreads();
    }
  }

  // ---- epilogue: D tile (j,i): col = i*16+rl of tq group, f = fhalf*32+j*16+gq*4 ----
  if (updup && uloc) return;            // skip duplicate u=24 stores
  const int u = u0 + uloc;
  const int fb = fhalf * 32 + gq * 4;
  const f32x4 z4 = (f32x4){0.f, 0.f, 0.f, 0.f};
#pragma unroll
  for (int i = 0; i < 4; ++i) {
    const int col = (tq * 4 + i) * 16 + rl;   // 0..127 within u-slot (t-rel, p-minor)
    const int t = t0 + (col >> 1);
    const int p = col & 1;
    if (t < 300) {
      float* dst = out + ((size_t)((b * 300 + t) * 3 + a) * 50 + (u * 2 + p)) * 64 + fb;
      const bool valid = (t < 292);     // t>=292: zero-pad tail
#pragma unroll
      for (int j = 0; j < 2; ++j) {
        f32x4 v = valid ? acc[j][i] : z4;
        *(f32x4*)(dst + j * 16) = v;
      }
    }
  }
}

extern "C" void kernel_launch(void* const* d_in, const int* in_sizes, int n_in,
                              void* d_out, int out_size, void* d_ws, size_t ws_size,
                              hipStream_t stream) {
  const float* x   = (const float*)d_in[0];
  const float* ker = (const float*)d_in[1];
  const int*   nb  = (const int*)d_in[2];
  float* out = (float*)d_out;

  w_prep<<<dim3(72), dim3(256), 0, stream>>>(ker, (u32x4*)d_ws);
  glc_mfma<<<dim3(8 * 3 * 13 * 5), dim3(512), 0, stream>>>(x, (const short8*)d_ws, nb, out);
}

// Round 7
// 145.056 us; speedup vs baseline: 1.1687x; 1.1226x over previous
//
#include <hip/hip_runtime.h>
#include <hip/hip_bf16.h>

typedef __attribute__((ext_vector_type(8))) short short8;
typedef __attribute__((ext_vector_type(4))) float f32x4;
typedef __attribute__((ext_vector_type(2))) unsigned int u32x2;
typedef __attribute__((ext_vector_type(4))) unsigned int u32x4;

#define SLAB 9216      // bytes per slot slab: 144 rows x 64B (32 bf16)
#define BUFB 18432     // per-step buffer: 2 slots

// involution swizzle: XOR bank-group bits (4-5) with row bits (7-8)
__device__ __forceinline__ unsigned sw(unsigned off) {
  return off ^ (((off >> 7) & 3u) << 4);
}

__device__ __forceinline__ unsigned pk2(float lo, float hi) {
  union { __hip_bfloat162 h; unsigned u; } c;
  c.h = __float22bfloat162_rn(float2{lo, hi});
  return c.u;
}

// one-time: ker (fp32, N*K x F x C) -> bf16 fragment-linear in ws
// frag(ch,nk,ft,lane) holds W[f=ft*16+(lane&15), c=ch*32+(lane>>4)*8 .. +8]
extern "C" __global__ void w_prep(const float* __restrict__ ker, u32x4* __restrict__ wsw) {
  const int nk = blockIdx.x % 36;
  const int ch = blockIdx.x / 36;
  const int lane = threadIdx.x & 63;
  const int ft = threadIdx.x >> 6;
  const float* src = ker + (size_t)(nk * 64 + ft * 16 + (lane & 15)) * 64
                         + ch * 32 + (lane >> 4) * 8;
  f32x4 a0 = *(const f32x4*)src;
  f32x4 a1 = *(const f32x4*)(src + 4);
  u32x4 h = { pk2(a0.x, a0.y), pk2(a0.z, a0.w), pk2(a1.x, a1.y), pk2(a1.z, a1.w) };
  wsw[((ch * 36 + nk) * 4 + ft) * 64 + lane] = h;
}

// one k-iteration: issue replacement W load first (keeps FIFO order favorable),
// then B ds_reads, then the setprio-wrapped MFMA cluster, then rotate W window.
#define KSTEP(KK, WREG, S2, K2) do {                                           \
    const int _wo = (((S2) & 1) * 9216) + (((S2) >> 1) * 2304) + ((K2) * 256) + fhl; \
    short8 _n0 = wqb[_wo];                                                     \
    short8 _n1 = wqb[_wo + 64];                                                \
    const unsigned _kq = cb + (unsigned)(((KK) >> 2) * 512) + poff[(KK) & 3];  \
    short8 _b0 = *(const short8*)(xs + _kq);                                   \
    short8 _b1 = *(const short8*)(xs + _kq + 1024u);                           \
    short8 _b2 = *(const short8*)(xs + _kq + 2048u);                           \
    short8 _b3 = *(const short8*)(xs + _kq + 3072u);                           \
    __builtin_amdgcn_s_setprio(1);                                             \
    acc[0][0] = __builtin_amdgcn_mfma_f32_16x16x32_bf16(WREG[0], _b0, acc[0][0], 0, 0, 0); \
    acc[1][0] = __builtin_amdgcn_mfma_f32_16x16x32_bf16(WREG[1], _b0, acc[1][0], 0, 0, 0); \
    acc[0][1] = __builtin_amdgcn_mfma_f32_16x16x32_bf16(WREG[0], _b1, acc[0][1], 0, 0, 0); \
    acc[1][1] = __builtin_amdgcn_mfma_f32_16x16x32_bf16(WREG[1], _b1, acc[1][1], 0, 0, 0); \
    acc[0][2] = __builtin_amdgcn_mfma_f32_16x16x32_bf16(WREG[0], _b2, acc[0][2], 0, 0, 0); \
    acc[1][2] = __builtin_amdgcn_mfma_f32_16x16x32_bf16(WREG[1], _b2, acc[1][2], 0, 0, 0); \
    acc[0][3] = __builtin_amdgcn_mfma_f32_16x16x32_bf16(WREG[0], _b3, acc[0][3], 0, 0, 0); \
    acc[1][3] = __builtin_amdgcn_mfma_f32_16x16x32_bf16(WREG[1], _b3, acc[1][3], 0, 0, 0); \
    __builtin_amdgcn_s_setprio(0);                                             \
    WREG[0] = _n0; WREG[1] = _n1;                                              \
  } while (0)

extern "C" __global__ __launch_bounds__(512, 4)
void glc_mfma(const float* __restrict__ x, const short8* __restrict__ wsw,
              const int* __restrict__ nb, float* __restrict__ out) {
  __shared__ __align__(16) char xs[2 * BUFB];

  const int bid = blockIdx.x;
  const int tt = bid % 5;
  const int up = (bid / 5) % 13;
  const int a  = (bid / 65) % 3;
  const int b  = bid / 195;
  const int t0 = tt * 64;
  const int u0 = up * 2;
  const bool updup = (up == 12);   // u-pair (24,24): odd waves duplicate

  const int tid  = threadIdx.x;
  const int lane = tid & 63;
  const int wave = tid >> 6;           // 0..7
  const int uloc = wave & 1;           // which u of the pair
  const int fhalf = (wave >> 1) & 1;   // which pair of f-tiles
  const int tq   = wave >> 2;          // which 4 col-tiles of the u-slot
  const int fhl  = fhalf * 128;

  const int su0 = u0;
  const int su1 = updup ? u0 : (u0 + 1);

  const int rl = lane & 15, gq = lane >> 4;
  unsigned poff[4];
#pragma unroll
  for (int m = 0; m < 4; ++m)
    poff[m] = sw((unsigned)((2 * m + rl) * 64 + gq * 16));

  f32x4 acc[2][4];
#pragma unroll
  for (int j = 0; j < 2; ++j)
#pragma unroll
    for (int i = 0; i < 4; ++i) acc[j][i] = (f32x4){0.f, 0.f, 0.f, 0.f};

  // ---- per-thread staging constants (computed once) ----
  int goff[5]; unsigned wroff[5]; int sel[5];
#pragma unroll
  for (int j = 0; j < 5; ++j) {
    const int u = j * 512 + tid;
    const int slot = (u >= 1152) ? 1 : 0;
    const int rem = u - slot * 1152;
    const int r = rem >> 3, q = rem & 7;
    int t = t0 + (r >> 1); if (t > 299) t = 299;   // clamp; garbage discarded
    goff[j] = t * 9600 + (r & 1) * 64 + q * 4;     // x fp32-element offset (v,ch terms per step)
    wroff[j] = (unsigned)(slot * SLAB) + sw((unsigned)(r * 64 + q * 8));
    sel[j] = slot;
  }
  const float* xb = x + (size_t)b * (300 * 9600) + (size_t)a * 3200;
  const short8* wqb = wsw + lane;

  f32x4 sr[5];
  auto stage_load = [&](int snx) {
    const int n2 = snx >> 1, ch2 = snx & 1;
    const int add0 = nb[su0 * 4 + n2] * 128 + ch2 * 32;
    const int add1 = nb[su1 * 4 + n2] * 128 + ch2 * 32;
#pragma unroll
    for (int j = 0; j < 5; ++j)
      if (j < 4 || tid < 256)
        sr[j] = *(const f32x4*)(xb + goff[j] + (sel[j] ? add1 : add0));
  };
  auto stage_write = [&](int snx) {
    char* dst = xs + (snx & 1) * BUFB;
#pragma unroll
    for (int j = 0; j < 5; ++j)
      if (j < 4 || tid < 256) {
        u32x2 h = { pk2(sr[j].x, sr[j].y), pk2(sr[j].z, sr[j].w) };
        *(u32x2*)(dst + wroff[j]) = h;
      }
  };

  // ---- prologue: W(0,0..2) issued BEFORE stage loads; stage step 0 ----
  short8 wA[2], wB[2], wC[2];
  {
    const int o0 = 0 * 256 + fhl, o1 = 1 * 256 + fhl, o2 = 2 * 256 + fhl;
    wA[0] = wqb[o0]; wA[1] = wqb[o0 + 64];
    wB[0] = wqb[o1]; wB[1] = wqb[o1 + 64];
    wC[0] = wqb[o2]; wC[1] = wqb[o2 + 64];
  }
  stage_load(0);
  stage_write(0);
  __syncthreads();

  // ---- main loop: 8 steps of (n = s>>1, ch = s&1) ----
#pragma unroll 1
  for (int s = 0; s < 8; ++s) {
    const int sn = (s < 7) ? (s + 1) : 7;      // s=7: dummy reloads (unused)
    if (s < 7) stage_load(s + 1);              // HBM loads: never block W waits now
    const unsigned cb = (unsigned)((s & 1) * BUFB + uloc * SLAB + tq * 4096);
    KSTEP(0, wA, s, 3);  KSTEP(1, wB, s, 4);  KSTEP(2, wC, s, 5);
    KSTEP(3, wA, s, 6);  KSTEP(4, wB, s, 7);  KSTEP(5, wC, s, 8);
    KSTEP(6, wA, sn, 0); KSTEP(7, wB, sn, 1); KSTEP(8, wC, sn, 2);
    if (s < 7) {
      stage_write(s + 1);                      // vmcnt wait lands after compute
      __syncthreads();
    }
  }

  // ---- epilogue: D tile (j,i): col = i*16+rl of tq group, f = fhalf*32+j*16+gq*4 ----
  if (updup && uloc) return;            // skip duplicate u=24 stores
  const int u = u0 + uloc;
  const int fb = fhalf * 32 + gq * 4;
  const f32x4 z4 = (f32x4){0.f, 0.f, 0.f, 0.f};
#pragma unroll
  for (int i = 0; i < 4; ++i) {
    const int col = (tq * 4 + i) * 16 + rl;   // 0..127 within u-slot (t-rel, p-minor)
    const int t = t0 + (col >> 1);
    const int p = col & 1;
    if (t < 300) {
      float* dst = out + ((size_t)((b * 300 + t) * 3 + a) * 50 + (u * 2 + p)) * 64 + fb;
      const bool valid = (t < 292);     // t>=292: zero-pad tail
#pragma unroll
      for (int j = 0; j < 2; ++j) {
        f32x4 v = valid ? acc[j][i] : z4;
        *(f32x4*)(dst + j * 16) = v;
      }
    }
  }
}

extern "C" void kernel_launch(void* const* d_in, const int* in_sizes, int n_in,
                              void* d_out, int out_size, void* d_ws, size_t ws_size,
                              hipStream_t stream) {
  const float* x   = (const float*)d_in[0];
  const float* ker = (const float*)d_in[1];
  const int*   nb  = (const int*)d_in[2];
  float* out = (float*)d_out;

  w_prep<<<dim3(72), dim3(256), 0, stream>>>(ker, (u32x4*)d_ws);
  glc_mfma<<<dim3(8 * 3 * 13 * 5), dim3(512), 0, stream>>>(x, (const short8*)d_ws, nb, out);
}